// Round 7
// baseline (1709.012 us; speedup 1.0000x reference)
//
#include <hip/hip_runtime.h>

// GINConvLayer: aggr = scatter_add(x[row] -> col); out = (1+eps)*x + aggr;
// h = out@W1^T + b1; BN(train stats) + ReLU; y = h@W2^T + b2.
// N=100000 nodes, C=128 ch, E=1600000 edges. fp32.
//
// R2: CSR pull (no float atomics): 2973 -> 668 us.
// R5: bf16 gather: 668 -> 598 us. k_fill now top (106MB write amp).
// R6: 64-node buckets: sequential pair scatter (write amp ~1), LDS-accum
//     bucket aggregation (no per-node CSR), BN stats fused into GEMM1.

constexpr int   NNODES = 100000;
constexpr int   CH     = 128;
constexpr long  NE     = 1600000;
constexpr float BN_EPS = 1e-5f;
constexpr int   NB     = (NNODES + 63) / 64;   // 1563 buckets of 64 nodes

__device__ __forceinline__ unsigned short f2b(float f) {
  unsigned int u = __float_as_uint(f);
  unsigned int r = (u + 0x7fffu + ((u >> 16) & 1u)) >> 16;  // RNE
  return (unsigned short)r;
}

// ---------------- x -> bf16 copy ----------------
__global__ __launch_bounds__(256) void k_x2b(const float* __restrict__ x,
                                             unsigned short* __restrict__ xb) {
  long i = (long)blockIdx.x * 256 + threadIdx.x;  // float4 group
  const long n4 = (long)NNODES * CH / 4;
  if (i >= n4) return;
  float4 v = reinterpret_cast<const float4*>(x)[i];
  ushort4 o;
  o.x = f2b(v.x); o.y = f2b(v.y); o.z = f2b(v.z); o.w = f2b(v.w);
  reinterpret_cast<ushort4*>(xb)[i] = o;
}

// ---------------- bucket histogram (LDS-reduced) ----------------
__global__ __launch_bounds__(256) void k_bhist(const int* __restrict__ ei,
                                               int* __restrict__ bcnt) {
  __shared__ int h[NB];
  for (int i = threadIdx.x; i < NB; i += 256) h[i] = 0;
  __syncthreads();
  for (long e = (long)blockIdx.x * 256 + threadIdx.x; e < NE;
       e += (long)gridDim.x * 256)
    atomicAdd(&h[ei[NE + e] >> 6], 1);
  __syncthreads();
  for (int i = threadIdx.x; i < NB; i += 256) {
    const int v = h[i];
    if (v) atomicAdd(&bcnt[i], v);
  }
}

// ---------------- bucket scan (1 block) ----------------
__global__ __launch_bounds__(1024) void k_bscan(const int* __restrict__ bcnt,
                                                int* __restrict__ boffs,
                                                int* __restrict__ bcur) {
  __shared__ int sm[1024];
  int carry = 0;
  for (int chunk = 0; chunk < NB; chunk += 1024) {
    const int i = chunk + threadIdx.x;
    const int v = (i < NB) ? bcnt[i] : 0;
    sm[threadIdx.x] = v;
    __syncthreads();
    for (int off = 1; off < 1024; off <<= 1) {
      int u = (threadIdx.x >= off) ? sm[threadIdx.x - off] : 0;
      __syncthreads();
      sm[threadIdx.x] += u;
      __syncthreads();
    }
    const int incl = sm[threadIdx.x] + carry;
    if (i < NB) { boffs[i] = incl - v; bcur[i] = incl - v; }
    if (i == NB - 1) boffs[NB] = incl;
    carry += sm[1023];      // uniform broadcast read (post-sync)
    __syncthreads();
  }
}

// ---------------- pair scatter (sequential per bucket) ----------------
__global__ __launch_bounds__(256) void k_pairs(const int* __restrict__ ei,
                                               int* __restrict__ bcur,
                                               unsigned int* __restrict__ pairs) {
  long e = (long)blockIdx.x * 256 + threadIdx.x;
  if (e >= NE) return;
  const int src = ei[e];
  const int dst = ei[NE + e];
  const int p = atomicAdd(&bcur[dst >> 6], 1);
  pairs[p] = ((unsigned int)src << 6) | (unsigned int)(dst & 63);
}

// ---------------- bucket aggregation ----------------
// One block per bucket. acc[plane][dl][l]: plane 0 = even channel 2l,
// plane 1 = odd channel 2l+1 -> LDS bank = l%32, 2-way aliasing (free).
__global__ __launch_bounds__(256) void k_baggr(const float* __restrict__ x,
                                               const unsigned int* __restrict__ xb32,
                                               const float* __restrict__ eps,
                                               const int* __restrict__ boffs,
                                               const unsigned int* __restrict__ pairs,
                                               float* __restrict__ out) {
  __shared__ float acc[2][64][64];   // 32 KB
  float* af = &acc[0][0][0];
  for (int i = threadIdx.x; i < 8192; i += 256) af[i] = 0.f;
  __syncthreads();
  const int b = blockIdx.x;
  const int beg = boffs[b], end = boffs[b + 1];
  const int w = threadIdx.x >> 6, lane = threadIdx.x & 63;
  for (int p = beg + w; p < end; p += 4) {
    const unsigned int word = pairs[p];          // wave-uniform broadcast
    const int src = (int)(word >> 6);
    const int dl  = (int)(word & 63u);
    const unsigned int u = xb32[(long)src * 64 + lane];
    atomicAdd(&acc[0][dl][lane], __uint_as_float(u << 16));
    atomicAdd(&acc[1][dl][lane], __uint_as_float(u & 0xffff0000u));
  }
  __syncthreads();
  const int node0 = b * 64;
  const float sc = 1.0f + eps[0];
  for (int g = threadIdx.x; g < 2048; g += 256) {  // 64 nodes x 32 float4
    const int dl = g >> 5;
    const int q  = g & 31;
    const int n  = node0 + dl;
    if (n < NNODES) {
      const float4 xv = *reinterpret_cast<const float4*>(x + (long)n * CH + q * 4);
      float4 o;
      o.x = fmaf(xv.x, sc, acc[0][dl][2 * q]);
      o.y = fmaf(xv.y, sc, acc[1][dl][2 * q]);
      o.z = fmaf(xv.z, sc, acc[0][dl][2 * q + 1]);
      o.w = fmaf(xv.w, sc, acc[1][dl][2 * q + 1]);
      *reinterpret_cast<float4*>(out + (long)n * CH + q * 4) = o;
    }
  }
}

// ---------------- GEMM: C = A @ W^T + bias ----------------
// BN: apply y=max(0,x*scale+shift) while staging A (layer 2).
// STATS: accumulate per-channel sum/sumsq of C into stats[0..255] (layer 1).
template <bool BN, bool STATS>
__global__ __launch_bounds__(256) void k_gemm(const float* __restrict__ A,
                                              const float* __restrict__ W,
                                              const float* __restrict__ bias,
                                              float* __restrict__ stats,
                                              float* __restrict__ Cout) {
  __shared__ float xs[64][132];
  __shared__ float wsT[32][132];
  const int tid  = threadIdx.x;
  const int row0 = blockIdx.x * 64;
  const int nrows = min(64, NNODES - row0);

  for (int l = 0; l < 8; ++l) {
    const int fi = l * 256 + tid;
    const int r  = fi >> 5;
    const int kq = fi & 31;
    float4 v = make_float4(0.f, 0.f, 0.f, 0.f);
    if (r < nrows)
      v = *reinterpret_cast<const float4*>(A + (long)(row0 + r) * CH + kq * 4);
    if (BN) {
      const int k = kq * 4;
      v.x = fmaxf(fmaf(v.x, stats[256 + k + 0], stats[384 + k + 0]), 0.f);
      v.y = fmaxf(fmaf(v.y, stats[256 + k + 1], stats[384 + k + 1]), 0.f);
      v.z = fmaxf(fmaf(v.z, stats[256 + k + 2], stats[384 + k + 2]), 0.f);
      v.w = fmaxf(fmaf(v.w, stats[256 + k + 3], stats[384 + k + 3]), 0.f);
    }
    *reinterpret_cast<float4*>(&xs[r][kq * 4]) = v;
  }

  float acc[4][8];
#pragma unroll
  for (int i = 0; i < 4; ++i)
#pragma unroll
    for (int j = 0; j < 8; ++j) acc[i][j] = 0.f;

  const int tc = tid & 15;
  const int tr = tid >> 4;
  const int r0 = tr * 4;
  const int c0 = tc * 8;

  for (int kb = 0; kb < 128; kb += 32) {
    __syncthreads();
#pragma unroll
    for (int l = 0; l < 16; ++l) {
      const int idx = l * 256 + tid;
      const int c   = idx >> 5;
      const int kk  = idx & 31;
      wsT[kk][c] = W[c * CH + kb + kk];
    }
    __syncthreads();
#pragma unroll
    for (int kk = 0; kk < 32; ++kk) {
      const float4 w0 = *reinterpret_cast<const float4*>(&wsT[kk][c0]);
      const float4 w1 = *reinterpret_cast<const float4*>(&wsT[kk][c0 + 4]);
      float xr[4];
#pragma unroll
      for (int i = 0; i < 4; ++i) xr[i] = xs[r0 + i][kb + kk];
#pragma unroll
      for (int i = 0; i < 4; ++i) {
        acc[i][0] = fmaf(xr[i], w0.x, acc[i][0]);
        acc[i][1] = fmaf(xr[i], w0.y, acc[i][1]);
        acc[i][2] = fmaf(xr[i], w0.z, acc[i][2]);
        acc[i][3] = fmaf(xr[i], w0.w, acc[i][3]);
        acc[i][4] = fmaf(xr[i], w1.x, acc[i][4]);
        acc[i][5] = fmaf(xr[i], w1.y, acc[i][5]);
        acc[i][6] = fmaf(xr[i], w1.z, acc[i][6]);
        acc[i][7] = fmaf(xr[i], w1.w, acc[i][7]);
      }
    }
  }

  // fold bias into acc, write C
  const float4 bv0 = *reinterpret_cast<const float4*>(bias + c0);
  const float4 bv1 = *reinterpret_cast<const float4*>(bias + c0 + 4);
#pragma unroll
  for (int i = 0; i < 4; ++i) {
    acc[i][0] += bv0.x; acc[i][1] += bv0.y; acc[i][2] += bv0.z; acc[i][3] += bv0.w;
    acc[i][4] += bv1.x; acc[i][5] += bv1.y; acc[i][6] += bv1.z; acc[i][7] += bv1.w;
    const int r = r0 + i;
    if (r < nrows) {
      float* p = Cout + (long)(row0 + r) * CH + c0;
      *reinterpret_cast<float4*>(p)     = make_float4(acc[i][0], acc[i][1], acc[i][2], acc[i][3]);
      *reinterpret_cast<float4*>(p + 4) = make_float4(acc[i][4], acc[i][5], acc[i][6], acc[i][7]);
    }
  }

  if (STATS) {
    __syncthreads();   // done reading xs; reuse as reduction scratch
    float2* sred = reinterpret_cast<float2*>(&xs[0][0]);  // [16][128] float2
#pragma unroll
    for (int j = 0; j < 8; ++j) {
      float s = 0.f, s2 = 0.f;
#pragma unroll
      for (int i = 0; i < 4; ++i)
        if (r0 + i < nrows) { const float v = acc[i][j]; s += v; s2 = fmaf(v, v, s2); }
      sred[tr * 128 + c0 + j] = make_float2(s, s2);
    }
    __syncthreads();
    if (tid < 128) {
      float s = 0.f, s2 = 0.f;
#pragma unroll
      for (int t = 0; t < 16; ++t) {
        const float2 v = sred[t * 128 + tid];
        s += v.x; s2 += v.y;
      }
      atomicAdd(&stats[tid], s);
      atomicAdd(&stats[128 + tid], s2);
    }
  }
}

__global__ __launch_bounds__(128) void k_finalize(float* __restrict__ stats,
                                                  const float* __restrict__ gamma,
                                                  const float* __restrict__ beta) {
  const int c = threadIdx.x;
  const float inv_n = 1.0f / (float)NNODES;
  const float mean = stats[c] * inv_n;
  const float var  = stats[CH + c] * inv_n - mean * mean;
  const float sc   = gamma[c] * rsqrtf(var + BN_EPS);
  stats[256 + c] = sc;
  stats[384 + c] = beta[c] - mean * sc;
}

extern "C" void kernel_launch(void* const* d_in, const int* in_sizes, int n_in,
                              void* d_out, int out_size, void* d_ws, size_t ws_size,
                              hipStream_t stream) {
  const float* x     = (const float*)d_in[0];
  const int*   ei    = (const int*)d_in[1];
  const float* eps   = (const float*)d_in[2];
  const float* W1    = (const float*)d_in[3];
  const float* b1    = (const float*)d_in[4];
  const float* gamma = (const float*)d_in[5];
  const float* beta  = (const float*)d_in[6];
  const float* W2    = (const float*)d_in[7];
  const float* b2    = (const float*)d_in[8];
  float* out = (float*)d_out;

  // workspace layout (~32.1 MB)
  unsigned short* xb = (unsigned short*)d_ws;              // N*CH bf16, 25.6 MB
  int* bcnt  = (int*)(xb + (long)NNODES * CH);             // NB
  int* boffs = bcnt + NB;                                  // NB+1
  int* bcur  = boffs + NB + 1;                             // NB
  unsigned int* pairs = (unsigned int*)(bcur + NB);        // NE, 6.4 MB
  float* stats = (float*)(pairs + NE);                     // 512 floats

  hipMemsetAsync(bcnt, 0, NB * sizeof(int), stream);
  hipMemsetAsync(stats, 0, 256 * sizeof(float), stream);

  const long n4 = (long)NNODES * CH / 4;
  k_x2b<<<(int)((n4 + 255) / 256), 256, 0, stream>>>(x, xb);

  const int eblk = (int)((NE + 255) / 256);
  k_bhist<<<256, 256, 0, stream>>>(ei, bcnt);
  k_bscan<<<1, 1024, 0, stream>>>(bcnt, boffs, bcur);
  k_pairs<<<eblk, 256, 0, stream>>>(ei, bcur, pairs);

  // bucket aggregation straight into d_out
  k_baggr<<<NB, 256, 0, stream>>>(x, (const unsigned int*)xb, eps, boffs, pairs, out);

  // h = out @ W1^T + b1, in-place on d_out; BN stats fused
  k_gemm<false, true><<<(NNODES + 63) / 64, 256, 0, stream>>>(out, W1, b1, stats, out);

  k_finalize<<<1, 128, 0, stream>>>(stats, gamma, beta);

  // y = relu(bn(h)) @ W2^T + b2, in-place on d_out
  k_gemm<true, false><<<(NNODES + 63) / 64, 256, 0, stream>>>(out, W2, b2, stats, out);
}